// Round 10
// baseline (189.675 us; speedup 1.0000x reference)
//
// Performer FAVOR+ on MI355X — R10: p1 at 2x occupancy. CROWS=128 (4096 waves,
// 4 blocks/CU), single-bf16 GEMM1 (fits 128-VGPR cap), in-block 4->1 LDS
// reduction keeps partials at 17 MB. p2 unchanged (at HBM roofline).
#include <hip/hip_runtime.h>

typedef short short8 __attribute__((ext_vector_type(8)));
typedef short s4b __attribute__((ext_vector_type(4)));
typedef float f32x4 __attribute__((ext_vector_type(4)));

namespace {
constexpr int Sc = 8192, Dc = 64;
constexpr int NH = 64;             // B*H heads
constexpr int CROWS = 128;         // rows per wave
constexpr int SLABS = CROWS / 16;  // 8 slabs of 16 rows
constexpr int PSTRIDE = 4160;      // 4096 B1 + 64 den
constexpr int PCHUNK = 16;         // partials per head (one per block)
// p2 chunking
constexpr int CH2 = 1024;
constexpr int TPT2 = CH2 / 64;
constexpr int NCHUNK2 = Sc / CH2;
}

__device__ __forceinline__ unsigned bf16rtne(float x) {
  unsigned u = __builtin_bit_cast(unsigned, x);
  return (u + 0x7fffu + ((u >> 16) & 1u)) >> 16;
}
__device__ __forceinline__ unsigned pkhl(float x) {
  unsigned u = __builtin_bit_cast(unsigned, x);
  unsigned rh = (u + 0x7fffu + ((u >> 16) & 1u)) & 0xffff0000u;
  float res = x - __builtin_bit_cast(float, rh);
  return (rh >> 16) | (__builtin_bit_cast(unsigned, res) & 0xffff0000u);
}
__device__ __forceinline__ void bsplit(float x, short& hi, short& lo) {
  unsigned p = pkhl(x);
  hi = (short)(p & 0xffff);
  lo = (short)(p >> 16);
}
__device__ __forceinline__ short8 exhi(uint4 q0, uint4 q1) {
  union { unsigned u[4]; short8 s; } r;
  r.u[0] = __builtin_amdgcn_perm(q0.y, q0.x, 0x05040100u);
  r.u[1] = __builtin_amdgcn_perm(q0.w, q0.z, 0x05040100u);
  r.u[2] = __builtin_amdgcn_perm(q1.y, q1.x, 0x05040100u);
  r.u[3] = __builtin_amdgcn_perm(q1.w, q1.z, 0x05040100u);
  return r.s;
}
__device__ __forceinline__ short8 exlo(uint4 q0, uint4 q1) {
  union { unsigned u[4]; short8 s; } r;
  r.u[0] = __builtin_amdgcn_perm(q0.y, q0.x, 0x07060302u);
  r.u[1] = __builtin_amdgcn_perm(q0.w, q0.z, 0x07060302u);
  r.u[2] = __builtin_amdgcn_perm(q1.y, q1.x, 0x07060302u);
  r.u[3] = __builtin_amdgcn_perm(q1.w, q1.z, 0x07060302u);
  return r.s;
}
// D = A*B + C for 16x16x16 bf16
__device__ __forceinline__ f32x4 mfma16(s4b a, s4b b, f32x4 c) {
#if __has_builtin(__builtin_amdgcn_mfma_f32_16x16x16bf16_1k)
  return __builtin_amdgcn_mfma_f32_16x16x16bf16_1k(a, b, c, 0, 0, 0);
#else
  f32x4 d;
  asm("v_mfma_f32_16x16x16_bf16 %0, %1, %2, %3" : "=v"(d) : "v"(a), "v"(b), "v"(c));
  return d;
#endif
}

__global__ void p0(const float* __restrict__ omega, short* __restrict__ wT) {
  int i = blockIdx.x * 256 + threadIdx.x;
  if (i < 4096) {
    int m = i >> 6, d = i & 63;
    short hi, lo;
    bsplit(omega[d * 64 + m], hi, lo);
    wT[m * 64 + d] = hi;
    wT[4096 + m * 64 + d] = lo;
  }
}

// ---------------- Phase 1: per-block partials of B1[m][c], den[m].
__global__ __launch_bounds__(256, 4) void p1(
    const float* __restrict__ Kg, const float* __restrict__ Vg,
    const short* __restrict__ wT, float* __restrict__ part) {
  __shared__ float red[2 * PSTRIDE];  // 33.3 KB (epilogue only)

  const int t = threadIdx.x;
  const int lane = t & 63;
  const int w = t >> 6;
  const int a = lane & 15;
  const int g = lane >> 4;
  const int h = blockIdx.x >> 4;        // head
  const int cb = blockIdx.x & 15;
  const int ci = cb * 4 + w;            // chunk 0..63 in head
  const float* Kb = Kg + ((size_t)h * Sc + (size_t)ci * CROWS) * Dc;
  const float* Vb = Vg + ((size_t)h * Sc + (size_t)ci * CROWS) * Dc;

  // omega B-frags (hi only): lane holds w[d=32ks+8g+j][m=16mt+a]
  short8 wfh[4][2];
#pragma unroll
  for (int mt = 0; mt < 4; ++mt)
#pragma unroll
    for (int ks = 0; ks < 2; ++ks)
      wfh[mt][ks] = *(const short8*)(wT + (16 * mt + a) * 64 + 32 * ks + 8 * g);

  f32x4 acc[4][4];
#pragma unroll
  for (int mt = 0; mt < 4; ++mt)
#pragma unroll
    for (int ct = 0; ct < 4; ++ct) acc[mt][ct] = (f32x4){0.f, 0.f, 0.f, 0.f};
  float dpart[4] = {0.f, 0.f, 0.f, 0.f};

  float4 kf[4];  // K[sb+a][8g.. | 32+8g..]  (A-frag f32)
  float vf[16];  // V[sb+4g+j][16ct+a]        (B-frag f32)
  auto loadK = [&](int sl) {
    const float* kb = Kb + ((size_t)sl * 16 + a) * 64 + 8 * g;
    kf[0] = *(const float4*)(kb);
    kf[1] = *(const float4*)(kb + 4);
    kf[2] = *(const float4*)(kb + 32);
    kf[3] = *(const float4*)(kb + 36);
  };
  auto loadV = [&](int sl) {
    const float* vb = Vb + ((size_t)sl * 16 + 4 * g) * 64 + a;
#pragma unroll
    for (int ct = 0; ct < 4; ++ct)
#pragma unroll
      for (int j = 0; j < 4; ++j) vf[ct * 4 + j] = vb[j * 64 + 16 * ct];
  };

  loadK(0);
  loadV(0);

  for (int sl = 0; sl < SLABS; ++sl) {
    // row sum-of-squares for row sb+a
    float ps = kf[0].x * kf[0].x + kf[0].y * kf[0].y + kf[0].z * kf[0].z + kf[0].w * kf[0].w;
    ps += kf[1].x * kf[1].x + kf[1].y * kf[1].y + kf[1].z * kf[1].z + kf[1].w * kf[1].w;
    ps += kf[2].x * kf[2].x + kf[2].y * kf[2].y + kf[2].z * kf[2].z + kf[2].w * kf[2].w;
    ps += kf[3].x * kf[3].x + kf[3].y * kf[3].y + kf[3].z * kf[3].z + kf[3].w * kf[3].w;
    ps += __shfl_xor(ps, 16, 64);
    ps += __shfl_xor(ps, 32, 64);

    // K -> single bf16 A-frags (hi only)
    short8 ah[2];
#pragma unroll
    for (int ks = 0; ks < 2; ++ks) {
      float v[8] = {kf[2 * ks].x, kf[2 * ks].y, kf[2 * ks].z, kf[2 * ks].w,
                    kf[2 * ks + 1].x, kf[2 * ks + 1].y, kf[2 * ks + 1].z, kf[2 * ks + 1].w};
#pragma unroll
      for (int i = 0; i < 8; ++i) ah[ks][i] = (short)bf16rtne(v[i]);
    }
    if (sl + 1 < SLABS) loadK(sl + 1);  // kf dead; prefetch

    // GEMM1: X[s][m] = K @ w  (single bf16; error washes out in the s-sum)
    f32x4 X[4];
#pragma unroll
    for (int mt = 0; mt < 4; ++mt) X[mt] = (f32x4){0.f, 0.f, 0.f, 0.f};
#pragma unroll
    for (int ks = 0; ks < 2; ++ks)
#pragma unroll
      for (int mt = 0; mt < 4; ++mt)
        X[mt] = __builtin_amdgcn_mfma_f32_16x16x32_bf16(ah[ks], wfh[mt][ks], X[mt], 0, 0, 0);

    // redistribute ssq to D-frag rows
    float sq[4];
#pragma unroll
    for (int r = 0; r < 4; ++r) sq[r] = __shfl(ps, 20 * g + r, 64);

    // exp -> P (f32 den; bf16 A-frag chained into GEMM2)
    s4b PA[4];
#pragma unroll
    for (int mt = 0; mt < 4; ++mt) {
#pragma unroll
      for (int r = 0; r < 4; ++r) {
        float p_ = 0.125f * __expf(X[mt][r] - 0.5f * sq[r]);
        dpart[mt] += p_;
        PA[mt][r] = (short)bf16rtne(p_);
      }
    }

    // V B-frag pack, then prefetch next V
    s4b VB[4];
#pragma unroll
    for (int ct = 0; ct < 4; ++ct)
#pragma unroll
      for (int j = 0; j < 4; ++j) VB[ct][j] = (short)bf16rtne(vf[ct * 4 + j]);
    if (sl + 1 < SLABS) loadV(sl + 1);

    // GEMM2: B1[m][c] += P^T @ V
#pragma unroll
    for (int mt = 0; mt < 4; ++mt)
#pragma unroll
      for (int ct = 0; ct < 4; ++ct) acc[mt][ct] = mfma16(PA[mt], VB[ct], acc[mt][ct]);
  }

  // ---- in-block 4->1 reduction via LDS (waves 0,1 write; 2,3 add) ----
  float dv[4];
#pragma unroll
  for (int mt = 0; mt < 4; ++mt) {
    float v = dpart[mt];
    v += __shfl_xor(v, 16, 64);
    v += __shfl_xor(v, 32, 64);
    dv[mt] = v;
  }
  if (w < 2) {
    float* rb = red + w * PSTRIDE;
#pragma unroll
    for (int mt = 0; mt < 4; ++mt)
#pragma unroll
      for (int ct = 0; ct < 4; ++ct)
#pragma unroll
        for (int r = 0; r < 4; ++r)
          rb[(16 * mt + 4 * g + r) * 64 + 16 * ct + a] = acc[mt][ct][r];
    if (g == 0) {
#pragma unroll
      for (int mt = 0; mt < 4; ++mt) rb[4096 + 16 * mt + a] = dv[mt];
    }
  }
  __syncthreads();
  if (w >= 2) {
    float* rb = red + (w - 2) * PSTRIDE;
#pragma unroll
    for (int mt = 0; mt < 4; ++mt)
#pragma unroll
      for (int ct = 0; ct < 4; ++ct)
#pragma unroll
        for (int r = 0; r < 4; ++r)
          rb[(16 * mt + 4 * g + r) * 64 + 16 * ct + a] += acc[mt][ct][r];
    if (g == 0) {
#pragma unroll
      for (int mt = 0; mt < 4; ++mt) rb[4096 + 16 * mt + a] += dv[mt];
    }
  }
  __syncthreads();
  float* pp = part + (size_t)blockIdx.x * PSTRIDE;
  for (int i = t; i < PSTRIDE; i += 256) pp[i] = red[i] + red[PSTRIDE + i];
}

// ---------------- p1r: reduce PCHUNK partials -> b1, den
__global__ __launch_bounds__(256) void p1r(
    const float* __restrict__ part, float* __restrict__ b1,
    float* __restrict__ den) {
  int o = blockIdx.x * 256 + threadIdx.x;
  if (o >= NH * PSTRIDE) return;
  int bh = o / PSTRIDE, i = o % PSTRIDE;
  const float* p = part + (size_t)bh * PCHUNK * PSTRIDE + i;
  float s = 0.f;
#pragma unroll
  for (int c = 0; c < PCHUNK; ++c) s += p[(size_t)c * PSTRIDE];
  if (i < 4096) b1[bh * 4096 + i] = s;
  else den[bh * 64 + (i - 4096)] = s;
}

// ---------------- Phase 2 (unchanged — at HBM roofline)
__global__ __launch_bounds__(256, 2) void p2(
    const float* __restrict__ Qg, const short* __restrict__ wT,
    const float* __restrict__ b1, const float* __restrict__ den,
    float* __restrict__ out) {
  __shared__ unsigned Qpk[64 * 68];
  __shared__ unsigned QP[64 * 68];
  __shared__ short B1h[64 * 72], B1l[64 * 72];
  __shared__ float denv[64];
  __shared__ float ssq[64];

  const int t = threadIdx.x;
  const int lane = t & 63;
  const int w = t >> 6;
  const int a = lane & 15;
  const int g = lane >> 4;
  const int bh = blockIdx.x / NCHUNK2, ch = blockIdx.x % NCHUNK2;
  const float* Qb = Qg + ((size_t)bh * Sc + (size_t)ch * CH2) * Dc;

  short8 wfh[4][2], wfl[4][2];
#pragma unroll
  for (int mt = 0; mt < 4; ++mt)
#pragma unroll
    for (int ks = 0; ks < 2; ++ks) {
      int off = (a + 16 * mt) * 64 + 32 * ks + 8 * g;
      wfh[mt][ks] = *(const short8*)(wT + off);
      wfl[mt][ks] = *(const short8*)(wT + 4096 + off);
    }

  const float* b1g = b1 + (size_t)bh * 4096;
  for (int i = t; i < 4096; i += 256) {
    int m = i >> 6, c = i & 63;
    short hi, lo;
    bsplit(b1g[i], hi, lo);
    B1h[c * 72 + m] = hi;
    B1l[c * 72 + m] = lo;
  }
  if (t < 64) denv[t] = den[bh * 64 + t];

  float4 qreg[4];
  auto load_tile = [&](int tile) {
    const float4* Qt = (const float4*)(Qb + (size_t)tile * 64 * Dc);
#pragma unroll
    for (int rr = 0; rr < 4; ++rr) qreg[rr] = Qt[rr * 256 + t];
  };
  auto store_tile = [&]() {
#pragma unroll
    for (int rr = 0; rr < 4; ++rr) {
      int idx = rr * 256 + t;
      int row = idx >> 4;
      int c4 = idx & 15;
      float4 kv = qreg[rr];
      uint4 qp;
      qp.x = pkhl(kv.x); qp.y = pkhl(kv.y);
      qp.z = pkhl(kv.z); qp.w = pkhl(kv.w);
      *(uint4*)&Qpk[row * 68 + 4 * c4] = qp;
      float ps = kv.x * kv.x + kv.y * kv.y + kv.z * kv.z + kv.w * kv.w;
      ps += __shfl_xor(ps, 1, 64); ps += __shfl_xor(ps, 2, 64);
      ps += __shfl_xor(ps, 4, 64); ps += __shfl_xor(ps, 8, 64);
      if (c4 == 0) ssq[row] = ps;
    }
  };

  load_tile(0);
  store_tile();
  __syncthreads();

  for (int tile = 0; tile < TPT2; ++tile) {
    if (tile + 1 < TPT2) load_tile(tile + 1);

    f32x4 X[4];
#pragma unroll
    for (int mt = 0; mt < 4; ++mt) X[mt] = (f32x4){0.f, 0.f, 0.f, 0.f};
#pragma unroll
    for (int ks = 0; ks < 2; ++ks) {
      const unsigned* qb = &Qpk[(16 * w + a) * 68 + 32 * ks + 8 * g];
      uint4 q0 = *(const uint4*)qb;
      uint4 q1 = *(const uint4*)(qb + 4);
      short8 ah = exhi(q0, q1), al = exlo(q0, q1);
#pragma unroll
      for (int mt = 0; mt < 4; ++mt) {
        X[mt] = __builtin_amdgcn_mfma_f32_16x16x32_bf16(ah, wfh[mt][ks], X[mt], 0, 0, 0);
        X[mt] = __builtin_amdgcn_mfma_f32_16x16x32_bf16(ah, wfl[mt][ks], X[mt], 0, 0, 0);
        X[mt] = __builtin_amdgcn_mfma_f32_16x16x32_bf16(al, wfh[mt][ks], X[mt], 0, 0, 0);
      }
    }

    float sq[4];
#pragma unroll
    for (int r = 0; r < 4; ++r) sq[r] = ssq[16 * w + 4 * g + r];
    float dv[4];
#pragma unroll
    for (int mt = 0; mt < 4; ++mt) dv[mt] = denv[16 * mt + a];
    float dn[4] = {0.f, 0.f, 0.f, 0.f};
#pragma unroll
    for (int mt = 0; mt < 4; ++mt) {
#pragma unroll
      for (int r = 0; r < 4; ++r) {
        float p_ = 0.125f * __expf(X[mt][r] - 0.5f * sq[r]);
        dn[r] = fmaf(p_, dv[mt], dn[r]);
        QP[(16 * w + 4 * g + r) * 68 + 16 * mt + a] = pkhl(p_);
      }
    }
#pragma unroll
    for (int r = 0; r < 4; ++r) {
      dn[r] += __shfl_xor(dn[r], 1, 64);
      dn[r] += __shfl_xor(dn[r], 2, 64);
      dn[r] += __shfl_xor(dn[r], 4, 64);
      dn[r] += __shfl_xor(dn[r], 8, 64);
    }
    __syncthreads();  // A

    f32x4 O[4];
#pragma unroll
    for (int ct = 0; ct < 4; ++ct) O[ct] = (f32x4){0.f, 0.f, 0.f, 0.f};
#pragma unroll
    for (int ks = 0; ks < 2; ++ks) {
      const unsigned* qb = &QP[(16 * w + a) * 68 + 32 * ks + 8 * g];
      uint4 r0 = *(const uint4*)qb;
      uint4 r1 = *(const uint4*)(qb + 4);
      short8 qh = exhi(r0, r1), ql = exlo(r0, r1);
#pragma unroll
      for (int ct = 0; ct < 4; ++ct) {
        short8 bh_ = *(const short8*)&B1h[(16 * ct + a) * 72 + 32 * ks + 8 * g];
        short8 bl_ = *(const short8*)&B1l[(16 * ct + a) * 72 + 32 * ks + 8 * g];
        O[ct] = __builtin_amdgcn_mfma_f32_16x16x32_bf16(qh, bh_, O[ct], 0, 0, 0);
        O[ct] = __builtin_amdgcn_mfma_f32_16x16x32_bf16(qh, bl_, O[ct], 0, 0, 0);
        O[ct] = __builtin_amdgcn_mfma_f32_16x16x32_bf16(ql, bh_, O[ct], 0, 0, 0);
      }
    }

    float inv[4];
#pragma unroll
    for (int r = 0; r < 4; ++r) inv[r] = 1.0f / dn[r];
    float* ob = out + ((size_t)bh * Sc + (size_t)ch * CH2 + tile * 64 + 16 * w + 4 * g) * 64;
#pragma unroll
    for (int ct = 0; ct < 4; ++ct)
#pragma unroll
      for (int r = 0; r < 4; ++r)
        ob[r * 64 + 16 * ct + a] = O[ct][r] * inv[r];
    __syncthreads();  // B
    if (tile + 1 < TPT2) store_tile();
    __syncthreads();  // C
  }
}

extern "C" void kernel_launch(void* const* d_in, const int* in_sizes, int n_in,
                              void* d_out, int out_size, void* d_ws, size_t ws_size,
                              hipStream_t stream) {
  const float* Q = (const float*)d_in[0];
  const float* K = (const float*)d_in[1];
  const float* V = (const float*)d_in[2];
  const float* omega = (const float*)d_in[3];
  float* outp = (float*)d_out;
  float* part = (float*)d_out;                 // 1024*4160*4B = 17 MB << 128 MB
  float* b1 = (float*)d_ws;                    // 64*4096 floats
  float* den = b1 + (size_t)NH * 4096;         // 64*64 floats
  short* wT = (short*)(den + NH * 64);         // 8192 shorts

  p0<<<16, 256, 0, stream>>>(omega, wT);
  p1<<<NH * PCHUNK, 256, 0, stream>>>(K, V, wT, part);   // 1024 blocks
  p1r<<<(NH * PSTRIDE + 255) / 256, 256, 0, stream>>>(part, b1, den);
  p2<<<NH * NCHUNK2, 256, 0, stream>>>(Q, wT, b1, den, outp);
}

// Round 11
// 189.351 us; speedup vs baseline: 1.0017x; 1.0017x over previous
//
// Performer FAVOR+ on MI355X — R11: p1 all-coalesced global loads; V transposed
// to B-frag via per-wave private LDS (XOR-swizzled, no barriers in main loop);
// chained GEMM1->GEMM2 as R10; chunked epilogue reduction (8.3 KB).
// p2 unchanged (at HBM roofline).
#include <hip/hip_runtime.h>

typedef short short8 __attribute__((ext_vector_type(8)));
typedef short s4b __attribute__((ext_vector_type(4)));
typedef float f32x4 __attribute__((ext_vector_type(4)));

namespace {
constexpr int Sc = 8192, Dc = 64;
constexpr int NH = 64;             // B*H heads
constexpr int CROWS = 128;         // rows per wave
constexpr int SLABS = CROWS / 16;  // 8 slabs of 16 rows
constexpr int PSTRIDE = 4160;      // 4096 B1 + 64 den
constexpr int PCHUNK = 16;         // partials per head (one per block)
// p2 chunking
constexpr int CH2 = 1024;
constexpr int TPT2 = CH2 / 64;
constexpr int NCHUNK2 = Sc / CH2;
}

__device__ __forceinline__ unsigned bf16rtne(float x) {
  unsigned u = __builtin_bit_cast(unsigned, x);
  return (u + 0x7fffu + ((u >> 16) & 1u)) >> 16;
}
__device__ __forceinline__ unsigned pkhl(float x) {
  unsigned u = __builtin_bit_cast(unsigned, x);
  unsigned rh = (u + 0x7fffu + ((u >> 16) & 1u)) & 0xffff0000u;
  float res = x - __builtin_bit_cast(float, rh);
  return (rh >> 16) | (__builtin_bit_cast(unsigned, res) & 0xffff0000u);
}
__device__ __forceinline__ void bsplit(float x, short& hi, short& lo) {
  unsigned p = pkhl(x);
  hi = (short)(p & 0xffff);
  lo = (short)(p >> 16);
}
__device__ __forceinline__ short8 exhi(uint4 q0, uint4 q1) {
  union { unsigned u[4]; short8 s; } r;
  r.u[0] = __builtin_amdgcn_perm(q0.y, q0.x, 0x05040100u);
  r.u[1] = __builtin_amdgcn_perm(q0.w, q0.z, 0x05040100u);
  r.u[2] = __builtin_amdgcn_perm(q1.y, q1.x, 0x05040100u);
  r.u[3] = __builtin_amdgcn_perm(q1.w, q1.z, 0x05040100u);
  return r.s;
}
__device__ __forceinline__ short8 exlo(uint4 q0, uint4 q1) {
  union { unsigned u[4]; short8 s; } r;
  r.u[0] = __builtin_amdgcn_perm(q0.y, q0.x, 0x07060302u);
  r.u[1] = __builtin_amdgcn_perm(q0.w, q0.z, 0x07060302u);
  r.u[2] = __builtin_amdgcn_perm(q1.y, q1.x, 0x07060302u);
  r.u[3] = __builtin_amdgcn_perm(q1.w, q1.z, 0x07060302u);
  return r.s;
}
// D = A*B + C for 16x16x16 bf16
__device__ __forceinline__ f32x4 mfma16(s4b a, s4b b, f32x4 c) {
#if __has_builtin(__builtin_amdgcn_mfma_f32_16x16x16bf16_1k)
  return __builtin_amdgcn_mfma_f32_16x16x16bf16_1k(a, b, c, 0, 0, 0);
#else
  f32x4 d;
  asm("v_mfma_f32_16x16x16_bf16 %0, %1, %2, %3" : "=v"(d) : "v"(a), "v"(b), "v"(c));
  return d;
#endif
}

__global__ void p0(const float* __restrict__ omega, short* __restrict__ wT) {
  int i = blockIdx.x * 256 + threadIdx.x;
  if (i < 4096) {
    int m = i >> 6, d = i & 63;
    short hi, lo;
    bsplit(omega[d * 64 + m], hi, lo);
    wT[m * 64 + d] = hi;
    wT[4096 + m * 64 + d] = lo;
  }
}

// ---------------- Phase 1: per-block partials of B1[m][c], den[m].
__global__ __launch_bounds__(256, 4) void p1(
    const float* __restrict__ Kg, const float* __restrict__ Vg,
    const short* __restrict__ wT, float* __restrict__ part) {
  __shared__ float VTs[4][64 * 20];  // per-wave V^T scratch, 20 KB
  __shared__ float red2[2][1040];    // epilogue chunk reduction, 8.3 KB

  const int t = threadIdx.x;
  const int lane = t & 63;
  const int w = t >> 6;
  const int a = lane & 15;
  const int g = lane >> 4;
  const int h = blockIdx.x >> 4;        // head
  const int cb = blockIdx.x & 15;
  const int ci = cb * 4 + w;            // chunk 0..63 in head
  const float* Kb = Kg + ((size_t)h * Sc + (size_t)ci * CROWS) * Dc;
  const float* Vb = Vg + ((size_t)h * Sc + (size_t)ci * CROWS) * Dc;
  float* VTw = VTs[w];

  // omega B-frags (hi only): lane holds w[d=32ks+8g+j][m=16mt+a]
  short8 wfh[4][2];
#pragma unroll
  for (int mt = 0; mt < 4; ++mt)
#pragma unroll
    for (int ks = 0; ks < 2; ++ks)
      wfh[mt][ks] = *(const short8*)(wT + (16 * mt + a) * 64 + 32 * ks + 8 * g);

  f32x4 acc[4][4];
#pragma unroll
  for (int mt = 0; mt < 4; ++mt)
#pragma unroll
    for (int ct = 0; ct < 4; ++ct) acc[mt][ct] = (f32x4){0.f, 0.f, 0.f, 0.f};
  float dpart[4] = {0.f, 0.f, 0.f, 0.f};

  float4 kf[4];    // K[sb+a][8g.. | 32+8g..]   (A-frag f32)
  float4 vreg[4];  // V rows coalesced: lane holds V[4q+g][4a..4a+3]
  auto loadK = [&](int sl) {
    const float* kb = Kb + ((size_t)sl * 16 + a) * 64 + 8 * g;
    kf[0] = *(const float4*)(kb);
    kf[1] = *(const float4*)(kb + 4);
    kf[2] = *(const float4*)(kb + 32);
    kf[3] = *(const float4*)(kb + 36);
  };
  auto loadV = [&](int sl) {
    const float4* Vt = (const float4*)(Vb + (size_t)sl * 16 * 64);
#pragma unroll
    for (int q = 0; q < 4; ++q) vreg[q] = Vt[q * 64 + lane];
  };
  // write vreg -> VTw[c*20 + (s ^ 4*(c&3))], c = 4a+i, s = 4q+g
  auto stageV = [&]() {
#pragma unroll
    for (int q = 0; q < 4; ++q) {
      float vv[4] = {vreg[q].x, vreg[q].y, vreg[q].z, vreg[q].w};
#pragma unroll
      for (int i = 0; i < 4; ++i)
        VTw[(4 * a + i) * 20 + ((4 * q + g) ^ (4 * i))] = vv[i];
    }
  };

  loadK(0);
  loadV(0);

  for (int sl = 0; sl < SLABS; ++sl) {
    stageV();                            // LDS writes in flight during GEMM1
    if (sl + 1 < SLABS) loadV(sl + 1);   // vreg consumed at issue; safe reuse

    // row sum-of-squares for row sb+a
    float ps = kf[0].x * kf[0].x + kf[0].y * kf[0].y + kf[0].z * kf[0].z + kf[0].w * kf[0].w;
    ps += kf[1].x * kf[1].x + kf[1].y * kf[1].y + kf[1].z * kf[1].z + kf[1].w * kf[1].w;
    ps += kf[2].x * kf[2].x + kf[2].y * kf[2].y + kf[2].z * kf[2].z + kf[2].w * kf[2].w;
    ps += kf[3].x * kf[3].x + kf[3].y * kf[3].y + kf[3].z * kf[3].z + kf[3].w * kf[3].w;
    ps += __shfl_xor(ps, 16, 64);
    ps += __shfl_xor(ps, 32, 64);

    // K -> single bf16 A-frags
    short8 ah[2];
#pragma unroll
    for (int ks = 0; ks < 2; ++ks) {
      float v[8] = {kf[2 * ks].x, kf[2 * ks].y, kf[2 * ks].z, kf[2 * ks].w,
                    kf[2 * ks + 1].x, kf[2 * ks + 1].y, kf[2 * ks + 1].z, kf[2 * ks + 1].w};
#pragma unroll
      for (int i = 0; i < 8; ++i) ah[ks][i] = (short)bf16rtne(v[i]);
    }
    if (sl + 1 < SLABS) loadK(sl + 1);

    // GEMM1: X[s][m] = K @ w (single bf16)
    f32x4 X[4];
#pragma unroll
    for (int mt = 0; mt < 4; ++mt) X[mt] = (f32x4){0.f, 0.f, 0.f, 0.f};
#pragma unroll
    for (int ks = 0; ks < 2; ++ks)
#pragma unroll
      for (int mt = 0; mt < 4; ++mt)
        X[mt] = __builtin_amdgcn_mfma_f32_16x16x32_bf16(ah[ks], wfh[mt][ks], X[mt], 0, 0, 0);

    // redistribute ssq to D-frag rows
    float sq[4];
#pragma unroll
    for (int r = 0; r < 4; ++r) sq[r] = __shfl(ps, 20 * g + r, 64);

    // exp -> P (f32 den; bf16 A-frag chained into GEMM2)
    s4b PA[4];
#pragma unroll
    for (int mt = 0; mt < 4; ++mt) {
#pragma unroll
      for (int r = 0; r < 4; ++r) {
        float p_ = 0.125f * __expf(X[mt][r] - 0.5f * sq[r]);
        dpart[mt] += p_;
        PA[mt][r] = (short)bf16rtne(p_);
      }
    }

    // V B-frags from LDS: lane needs V[4g+j][16ct+a], j in x..w order
    s4b VB[4];
#pragma unroll
    for (int ct = 0; ct < 4; ++ct) {
      float4 vv = *(const float4*)&VTw[(16 * ct + a) * 20 + 4 * (g ^ (a & 3))];
      VB[ct][0] = (short)bf16rtne(vv.x);
      VB[ct][1] = (short)bf16rtne(vv.y);
      VB[ct][2] = (short)bf16rtne(vv.z);
      VB[ct][3] = (short)bf16rtne(vv.w);
    }

    // GEMM2: B1[m][c] += P^T @ V
#pragma unroll
    for (int mt = 0; mt < 4; ++mt)
#pragma unroll
      for (int ct = 0; ct < 4; ++ct) acc[mt][ct] = mfma16(PA[mt], VB[ct], acc[mt][ct]);
  }

  // den: reduce within wave (over g groups)
  float dv[4];
#pragma unroll
  for (int mt = 0; mt < 4; ++mt) {
    float v = dpart[mt];
    v += __shfl_xor(v, 16, 64);
    v += __shfl_xor(v, 32, 64);
    dv[mt] = v;
  }

  // chunked in-block 4->1 reduction (per mt: 16 rows x 64 cols + 16 den)
  float* pp = part + (size_t)blockIdx.x * PSTRIDE;
#pragma unroll
  for (int mt = 0; mt < 4; ++mt) {
    __syncthreads();
    if (w < 2) {
#pragma unroll
      for (int ct = 0; ct < 4; ++ct)
#pragma unroll
        for (int r = 0; r < 4; ++r)
          red2[w][(4 * g + r) * 64 + 16 * ct + a] = acc[mt][ct][r];
      if (g == 0) red2[w][1024 + a] = dv[mt];
    }
    __syncthreads();
    if (w >= 2) {
#pragma unroll
      for (int ct = 0; ct < 4; ++ct)
#pragma unroll
        for (int r = 0; r < 4; ++r)
          red2[w - 2][(4 * g + r) * 64 + 16 * ct + a] += acc[mt][ct][r];
      if (g == 0) red2[w - 2][1024 + a] += dv[mt];
    }
    __syncthreads();
    for (int i = t; i < 1024; i += 256)
      pp[16 * mt * 64 + i] = red2[0][i] + red2[1][i];
    if (t < 16) pp[4096 + 16 * mt + t] = red2[0][1024 + t] + red2[1][1024 + t];
  }
}

// ---------------- p1r: reduce PCHUNK partials -> b1, den
__global__ __launch_bounds__(256) void p1r(
    const float* __restrict__ part, float* __restrict__ b1,
    float* __restrict__ den) {
  int o = blockIdx.x * 256 + threadIdx.x;
  if (o >= NH * PSTRIDE) return;
  int bh = o / PSTRIDE, i = o % PSTRIDE;
  const float* p = part + (size_t)bh * PCHUNK * PSTRIDE + i;
  float s = 0.f;
#pragma unroll
  for (int c = 0; c < PCHUNK; ++c) s += p[(size_t)c * PSTRIDE];
  if (i < 4096) b1[bh * 4096 + i] = s;
  else den[bh * 64 + (i - 4096)] = s;
}

// ---------------- Phase 2 (unchanged — at HBM roofline)
__global__ __launch_bounds__(256, 2) void p2(
    const float* __restrict__ Qg, const short* __restrict__ wT,
    const float* __restrict__ b1, const float* __restrict__ den,
    float* __restrict__ out) {
  __shared__ unsigned Qpk[64 * 68];
  __shared__ unsigned QP[64 * 68];
  __shared__ short B1h[64 * 72], B1l[64 * 72];
  __shared__ float denv[64];
  __shared__ float ssq[64];

  const int t = threadIdx.x;
  const int lane = t & 63;
  const int w = t >> 6;
  const int a = lane & 15;
  const int g = lane >> 4;
  const int bh = blockIdx.x / NCHUNK2, ch = blockIdx.x % NCHUNK2;
  const float* Qb = Qg + ((size_t)bh * Sc + (size_t)ch * CH2) * Dc;

  short8 wfh[4][2], wfl[4][2];
#pragma unroll
  for (int mt = 0; mt < 4; ++mt)
#pragma unroll
    for (int ks = 0; ks < 2; ++ks) {
      int off = (a + 16 * mt) * 64 + 32 * ks + 8 * g;
      wfh[mt][ks] = *(const short8*)(wT + off);
      wfl[mt][ks] = *(const short8*)(wT + 4096 + off);
    }

  const float* b1g = b1 + (size_t)bh * 4096;
  for (int i = t; i < 4096; i += 256) {
    int m = i >> 6, c = i & 63;
    short hi, lo;
    bsplit(b1g[i], hi, lo);
    B1h[c * 72 + m] = hi;
    B1l[c * 72 + m] = lo;
  }
  if (t < 64) denv[t] = den[bh * 64 + t];

  float4 qreg[4];
  auto load_tile = [&](int tile) {
    const float4* Qt = (const float4*)(Qb + (size_t)tile * 64 * Dc);
#pragma unroll
    for (int rr = 0; rr < 4; ++rr) qreg[rr] = Qt[rr * 256 + t];
  };
  auto store_tile = [&]() {
#pragma unroll
    for (int rr = 0; rr < 4; ++rr) {
      int idx = rr * 256 + t;
      int row = idx >> 4;
      int c4 = idx & 15;
      float4 kv = qreg[rr];
      uint4 qp;
      qp.x = pkhl(kv.x); qp.y = pkhl(kv.y);
      qp.z = pkhl(kv.z); qp.w = pkhl(kv.w);
      *(uint4*)&Qpk[row * 68 + 4 * c4] = qp;
      float ps = kv.x * kv.x + kv.y * kv.y + kv.z * kv.z + kv.w * kv.w;
      ps += __shfl_xor(ps, 1, 64); ps += __shfl_xor(ps, 2, 64);
      ps += __shfl_xor(ps, 4, 64); ps += __shfl_xor(ps, 8, 64);
      if (c4 == 0) ssq[row] = ps;
    }
  };

  load_tile(0);
  store_tile();
  __syncthreads();

  for (int tile = 0; tile < TPT2; ++tile) {
    if (tile + 1 < TPT2) load_tile(tile + 1);

    f32x4 X[4];
#pragma unroll
    for (int mt = 0; mt < 4; ++mt) X[mt] = (f32x4){0.f, 0.f, 0.f, 0.f};
#pragma unroll
    for (int ks = 0; ks < 2; ++ks) {
      const unsigned* qb = &Qpk[(16 * w + a) * 68 + 32 * ks + 8 * g];
      uint4 q0 = *(const uint4*)qb;
      uint4 q1 = *(const uint4*)(qb + 4);
      short8 ah = exhi(q0, q1), al = exlo(q0, q1);
#pragma unroll
      for (int mt = 0; mt < 4; ++mt) {
        X[mt] = __builtin_amdgcn_mfma_f32_16x16x32_bf16(ah, wfh[mt][ks], X[mt], 0, 0, 0);
        X[mt] = __builtin_amdgcn_mfma_f32_16x16x32_bf16(ah, wfl[mt][ks], X[mt], 0, 0, 0);
        X[mt] = __builtin_amdgcn_mfma_f32_16x16x32_bf16(al, wfh[mt][ks], X[mt], 0, 0, 0);
      }
    }

    float sq[4];
#pragma unroll
    for (int r = 0; r < 4; ++r) sq[r] = ssq[16 * w + 4 * g + r];
    float dv[4];
#pragma unroll
    for (int mt = 0; mt < 4; ++mt) dv[mt] = denv[16 * mt + a];
    float dn[4] = {0.f, 0.f, 0.f, 0.f};
#pragma unroll
    for (int mt = 0; mt < 4; ++mt) {
#pragma unroll
      for (int r = 0; r < 4; ++r) {
        float p_ = 0.125f * __expf(X[mt][r] - 0.5f * sq[r]);
        dn[r] = fmaf(p_, dv[mt], dn[r]);
        QP[(16 * w + 4 * g + r) * 68 + 16 * mt + a] = pkhl(p_);
      }
    }
#pragma unroll
    for (int r = 0; r < 4; ++r) {
      dn[r] += __shfl_xor(dn[r], 1, 64);
      dn[r] += __shfl_xor(dn[r], 2, 64);
      dn[r] += __shfl_xor(dn[r], 4, 64);
      dn[r] += __shfl_xor(dn[r], 8, 64);
    }
    __syncthreads();  // A

    f32x4 O[4];
#pragma unroll
    for (int ct = 0; ct < 4; ++ct) O[ct] = (f32x4){0.f, 0.f, 0.f, 0.f};
#pragma unroll
    for (int ks = 0; ks < 2; ++ks) {
      const unsigned* qb = &QP[(16 * w + a) * 68 + 32 * ks + 8 * g];
      uint4 r0 = *(const uint4*)qb;
      uint4 r1 = *(const uint4*)(qb + 4);
      short8 qh = exhi(r0, r1), ql = exlo(r0, r1);
#pragma unroll
      for (int ct = 0; ct < 4; ++ct) {
        short8 bh_ = *(const short8*)&B1h[(16 * ct + a) * 72 + 32 * ks + 8 * g];
        short8 bl_ = *(const short8*)&B1l[(16 * ct + a) * 72 + 32 * ks + 8 * g];
        O[ct] = __builtin_amdgcn_mfma_f32_16x16x32_bf16(qh, bh_, O[ct], 0, 0, 0);
        O[ct] = __builtin_amdgcn_mfma_f32_16x16x32_bf16(qh, bl_, O[ct], 0, 0, 0);
        O[ct] = __builtin_amdgcn_mfma_f32_16x16x32_bf16(ql, bh_, O[ct], 0, 0, 0);
      }
    }

    float inv[4];
#pragma unroll
    for (int r = 0; r < 4; ++r) inv[r] = 1.0f / dn[r];
    float* ob = out + ((size_t)bh * Sc + (size_t)ch * CH2 + tile * 64 + 16 * w + 4 * g) * 64;
#pragma unroll
    for (int ct = 0; ct < 4; ++ct)
#pragma unroll
      for (int r = 0; r < 4; ++r)
        ob[r * 64 + 16 * ct + a] = O[ct][r] * inv[r];
    __syncthreads();  // B
    if (tile + 1 < TPT2) store_tile();
    __syncthreads();  // C
  }
}

extern "C" void kernel_launch(void* const* d_in, const int* in_sizes, int n_in,
                              void* d_out, int out_size, void* d_ws, size_t ws_size,
                              hipStream_t stream) {
  const float* Q = (const float*)d_in[0];
  const float* K = (const float*)d_in[1];
  const float* V = (const float*)d_in[2];
  const float* omega = (const float*)d_in[3];
  float* outp = (float*)d_out;
  float* part = (float*)d_out;                 // 1024*4160*4B = 17 MB << 128 MB
  float* b1 = (float*)d_ws;                    // 64*4096 floats
  float* den = b1 + (size_t)NH * 4096;         // 64*64 floats
  short* wT = (short*)(den + NH * 64);         // 8192 shorts

  p0<<<16, 256, 0, stream>>>(omega, wT);
  p1<<<NH * PCHUNK, 256, 0, stream>>>(K, V, wT, part);   // 1024 blocks
  p1r<<<(NH * PSTRIDE + 255) / 256, 256, 0, stream>>>(part, b1, den);
  p2<<<NH * NCHUNK2, 256, 0, stream>>>(Q, wT, b1, den, outp);
}

// Round 12
// 146.912 us; speedup vs baseline: 1.2911x; 1.2889x over previous
//
// Performer FAVOR+ on MI355X — R12: R6 base (best-known) + lgkm-only barriers
// (prefetch stays in flight across s_barrier) + single-bf16 GEMM1 in p1.
// p2 unchanged (at HBM roofline).
#include <hip/hip_runtime.h>

typedef short short8 __attribute__((ext_vector_type(8)));
typedef float f32x4 __attribute__((ext_vector_type(4)));

namespace {
constexpr int Sc = 8192, Dc = 64;
constexpr int NH = 64;                 // B*H heads
constexpr int CH = 1024;               // rows per block
constexpr int TPT = CH / 64;           // 16 tiles of 64 rows
constexpr int NCHUNK = Sc / CH;        // 8
constexpr size_t DEN_OFF = (size_t)NH * 4096;            // floats
constexpr size_t WT_OFF_BYTES = (DEN_OFF + NH * 64) * 4; // bytes
}

// barrier that drains only LDS ops; global loads stay in flight
__device__ __forceinline__ void lds_barrier() {
  __builtin_amdgcn_sched_barrier(0);
  asm volatile("s_waitcnt lgkmcnt(0)" ::: "memory");
  __builtin_amdgcn_s_barrier();
  __builtin_amdgcn_sched_barrier(0);
}

__device__ __forceinline__ unsigned bf16rtne(float x) {
  unsigned u = __builtin_bit_cast(unsigned, x);
  return (u + 0x7fffu + ((u >> 16) & 1u)) >> 16;
}
// pack f32 -> (bf16_hi RTNE) | (bf16_lo residual) << 16
__device__ __forceinline__ unsigned pkhl(float x) {
  unsigned u = __builtin_bit_cast(unsigned, x);
  unsigned rh = (u + 0x7fffu + ((u >> 16) & 1u)) & 0xffff0000u;
  float res = x - __builtin_bit_cast(float, rh);
  return (rh >> 16) | (__builtin_bit_cast(unsigned, res) & 0xffff0000u);
}
__device__ __forceinline__ void bsplit(float x, short& hi, short& lo) {
  unsigned p = pkhl(x);
  hi = (short)(p & 0xffff);
  lo = (short)(p >> 16);
}
__device__ __forceinline__ short8 exhi(uint4 q0, uint4 q1) {
  union { unsigned u[4]; short8 s; } r;
  r.u[0] = __builtin_amdgcn_perm(q0.y, q0.x, 0x05040100u);
  r.u[1] = __builtin_amdgcn_perm(q0.w, q0.z, 0x05040100u);
  r.u[2] = __builtin_amdgcn_perm(q1.y, q1.x, 0x05040100u);
  r.u[3] = __builtin_amdgcn_perm(q1.w, q1.z, 0x05040100u);
  return r.s;
}
__device__ __forceinline__ short8 exlo(uint4 q0, uint4 q1) {
  union { unsigned u[4]; short8 s; } r;
  r.u[0] = __builtin_amdgcn_perm(q0.y, q0.x, 0x07060302u);
  r.u[1] = __builtin_amdgcn_perm(q0.w, q0.z, 0x07060302u);
  r.u[2] = __builtin_amdgcn_perm(q1.y, q1.x, 0x07060302u);
  r.u[3] = __builtin_amdgcn_perm(q1.w, q1.z, 0x07060302u);
  return r.s;
}

__global__ void p0(const float* __restrict__ omega, short* __restrict__ wT) {
  int i = blockIdx.x * 256 + threadIdx.x;
  if (i < 4096) {
    int m = i >> 6, d = i & 63;
    short hi, lo;
    bsplit(omega[d * 64 + m], hi, lo);
    wT[m * 64 + d] = hi;
    wT[4096 + m * 64 + d] = lo;
  }
}

// ---------------- Phase 1: B1[m][c] = sum_s k'[s][m] V[s][c]; den[m] = sum_s k'[s][m]
__global__ __launch_bounds__(256, 2) void p1(
    const float* __restrict__ Kg, const float* __restrict__ Vg,
    const short* __restrict__ wT, float* __restrict__ b1, float* __restrict__ den) {
  __shared__ unsigned Kpk[64 * 68];  // K tile packed hi|lo, [row][d] stride 68
  __shared__ unsigned VT[64 * 68];   // V^T bf16 in low16, [c][s ^ 4*((c>>3)&7)]
  __shared__ unsigned PT[64 * 68];   // k'^T bf16 in low16, [m][s] stride 68
  __shared__ float ssq[64];

  const int t = threadIdx.x;
  const int lane = t & 63;
  const int w = t >> 6;      // wave 0..3
  const int a = lane & 15;
  const int g = lane >> 4;   // 0..3
  const int bh = blockIdx.x / NCHUNK, ch = blockIdx.x % NCHUNK;
  const float* Kb = Kg + ((size_t)bh * Sc + (size_t)ch * CH) * Dc;
  const float* Vb = Vg + ((size_t)bh * Sc + (size_t)ch * CH) * Dc;

  // omega B-frags (hi only — single-bf16 GEMM1, validated R10/R11):
  // lane holds w[d=32ks+8g+j][m=16mt+a]
  short8 wfh[4][2];
#pragma unroll
  for (int mt = 0; mt < 4; ++mt)
#pragma unroll
    for (int ks = 0; ks < 2; ++ks)
      wfh[mt][ks] = *(const short8*)(wT + (a + 16 * mt) * 64 + 32 * ks + 8 * g);

  float4 kreg[4], vreg[4];
  auto load_tile = [&](int tile) {
    const float4* Kt = (const float4*)(Kb + (size_t)tile * 64 * Dc);
    const float4* Vt = (const float4*)(Vb + (size_t)tile * 64 * Dc);
#pragma unroll
    for (int rr = 0; rr < 4; ++rr) {
      kreg[rr] = Kt[rr * 256 + t];
      vreg[rr] = Vt[rr * 256 + t];
    }
  };
  auto store_tile = [&]() {
#pragma unroll
    for (int rr = 0; rr < 4; ++rr) {
      int idx = rr * 256 + t;
      int row = idx >> 4;   // 0..63
      int c4 = idx & 15;
      float4 kv = kreg[rr];
      uint4 kp;
      kp.x = pkhl(kv.x); kp.y = pkhl(kv.y);
      kp.z = pkhl(kv.z); kp.w = pkhl(kv.w);
      *(uint4*)&Kpk[row * 68 + 4 * c4] = kp;  // uniform-8 banks
      float ps = kv.x * kv.x + kv.y * kv.y + kv.z * kv.z + kv.w * kv.w;
      ps += __shfl_xor(ps, 1, 64); ps += __shfl_xor(ps, 2, 64);
      ps += __shfl_xor(ps, 4, 64); ps += __shfl_xor(ps, 8, 64);
      if (c4 == 0) ssq[row] = ps;
      // V transpose, XOR-swizzled s (2-way writes); single bf16 in low16
      float4 vv = vreg[rr];
      int sw = row ^ (4 * ((c4 >> 1) & 7));
      VT[(4 * c4 + 0) * 68 + sw] = bf16rtne(vv.x);
      VT[(4 * c4 + 1) * 68 + sw] = bf16rtne(vv.y);
      VT[(4 * c4 + 2) * 68 + sw] = bf16rtne(vv.z);
      VT[(4 * c4 + 3) * 68 + sw] = bf16rtne(vv.w);
    }
  };

  f32x4 B1a[4];
#pragma unroll
  for (int ct = 0; ct < 4; ++ct) B1a[ct] = (f32x4){0.f, 0.f, 0.f, 0.f};
  float dpart[4] = {0.f, 0.f, 0.f, 0.f};

  load_tile(0);
  store_tile();
  lds_barrier();

  for (int tile = 0; tile < TPT; ++tile) {
    if (tile + 1 < TPT) load_tile(tile + 1);  // stays in flight across barriers

    // GEMM1: X[s][m] = K @ omega (single bf16)
    f32x4 X[4];
#pragma unroll
    for (int mt = 0; mt < 4; ++mt) X[mt] = (f32x4){0.f, 0.f, 0.f, 0.f};
#pragma unroll
    for (int ks = 0; ks < 2; ++ks) {
      const unsigned* kb = &Kpk[(16 * w + a) * 68 + 32 * ks + 8 * g];
      uint4 q0 = *(const uint4*)kb;
      uint4 q1 = *(const uint4*)(kb + 4);
      short8 ah = exhi(q0, q1);
#pragma unroll
      for (int mt = 0; mt < 4; ++mt)
        X[mt] = __builtin_amdgcn_mfma_f32_16x16x32_bf16(ah, wfh[mt][ks], X[mt], 0, 0, 0);
    }

    // exp -> k'; f32 for den, single bf16 (low16) for the P@V product
    float sq[4];
#pragma unroll
    for (int r = 0; r < 4; ++r) sq[r] = ssq[16 * w + 4 * g + r];
#pragma unroll
    for (int mt = 0; mt < 4; ++mt) {
      uint4 pp;
      float p_;
      p_ = 0.125f * __expf(X[mt][0] - 0.5f * sq[0]); dpart[mt] += p_; pp.x = bf16rtne(p_);
      p_ = 0.125f * __expf(X[mt][1] - 0.5f * sq[1]); dpart[mt] += p_; pp.y = bf16rtne(p_);
      p_ = 0.125f * __expf(X[mt][2] - 0.5f * sq[2]); dpart[mt] += p_; pp.z = bf16rtne(p_);
      p_ = 0.125f * __expf(X[mt][3] - 0.5f * sq[3]); dpart[mt] += p_; pp.w = bf16rtne(p_);
      *(uint4*)&PT[(16 * mt + a) * 68 + 16 * w + 4 * g] = pp;  // uniform-8
    }
    lds_barrier();  // A: PT visible, Kpk reads done (LDS only)

    // GEMM2: B1 += P^T @ V  (single bf16, 1 MFMA per fragment)
#pragma unroll
    for (int ks = 0; ks < 2; ++ks) {
      const unsigned* pb = &PT[(16 * w + a) * 68 + 32 * ks + 8 * g];
      uint4 r0 = *(const uint4*)pb;
      uint4 r1 = *(const uint4*)(pb + 4);
      short8 pah = exhi(r0, r1);
#pragma unroll
      for (int ct = 0; ct < 4; ++ct) {
        int c = 16 * ct + a;
        int kk4 = 4 * ((2 * ct + (a >> 3)) & 7);
        int s0 = (32 * ks + 8 * g) ^ kk4;
        int s1 = (32 * ks + 8 * g + 4) ^ kk4;
        const unsigned* vb = &VT[c * 68];
        uint4 v0 = *(const uint4*)(vb + s0);
        uint4 v1 = *(const uint4*)(vb + s1);
        short8 vh = exhi(v0, v1);
        B1a[ct] = __builtin_amdgcn_mfma_f32_16x16x32_bf16(pah, vh, B1a[ct], 0, 0, 0);
      }
    }
    lds_barrier();  // B: VT/PT reads done
    if (tile + 1 < TPT) store_tile();  // vmcnt wait lands here only
    lds_barrier();  // C: staged data visible
  }

  float* b1h = b1 + (size_t)bh * 4096;
#pragma unroll
  for (int ct = 0; ct < 4; ++ct)
#pragma unroll
    for (int r = 0; r < 4; ++r)
      atomicAdd(&b1h[(16 * w + 4 * g + r) * 64 + 16 * ct + a], B1a[ct][r]);
#pragma unroll
  for (int mt = 0; mt < 4; ++mt) {
    float v = dpart[mt];
    v += __shfl_xor(v, 16, 64);
    v += __shfl_xor(v, 32, 64);
    if (g == 0) atomicAdd(&den[bh * 64 + 16 * mt + a], v);
  }
}

// ---------------- Phase 2 (unchanged from R6 — at HBM roofline)
__global__ __launch_bounds__(256, 2) void p2(
    const float* __restrict__ Qg, const short* __restrict__ wT,
    const float* __restrict__ b1, const float* __restrict__ den,
    float* __restrict__ out) {
  __shared__ unsigned Qpk[64 * 68];
  __shared__ unsigned QP[64 * 68];
  __shared__ short B1h[64 * 72], B1l[64 * 72];
  __shared__ float denv[64];
  __shared__ float ssq[64];

  const int t = threadIdx.x;
  const int lane = t & 63;
  const int w = t >> 6;
  const int a = lane & 15;
  const int g = lane >> 4;
  const int bh = blockIdx.x / NCHUNK, ch = blockIdx.x % NCHUNK;
  const float* Qb = Qg + ((size_t)bh * Sc + (size_t)ch * CH) * Dc;

  short8 wfh[4][2], wfl[4][2];
#pragma unroll
  for (int mt = 0; mt < 4; ++mt)
#pragma unroll
    for (int ks = 0; ks < 2; ++ks) {
      int off = (a + 16 * mt) * 64 + 32 * ks + 8 * g;
      wfh[mt][ks] = *(const short8*)(wT + off);
      wfl[mt][ks] = *(const short8*)(wT + 4096 + off);
    }

  const float* b1g = b1 + (size_t)bh * 4096;
  for (int i = t; i < 4096; i += 256) {
    int m = i >> 6, c = i & 63;
    short hi, lo;
    bsplit(b1g[i], hi, lo);
    B1h[c * 72 + m] = hi;
    B1l[c * 72 + m] = lo;
  }
  if (t < 64) denv[t] = den[bh * 64 + t];

  float4 qreg[4];
  auto load_tile = [&](int tile) {
    const float4* Qt = (const float4*)(Qb + (size_t)tile * 64 * Dc);
#pragma unroll
    for (int rr = 0; rr < 4; ++rr) qreg[rr] = Qt[rr * 256 + t];
  };
  auto store_tile = [&]() {
#pragma unroll
    for (int rr = 0; rr < 4; ++rr) {
      int idx = rr * 256 + t;
      int row = idx >> 4;
      int c4 = idx & 15;
      float4 kv = qreg[rr];
      uint4 qp;
      qp.x = pkhl(kv.x); qp.y = pkhl(kv.y);
      qp.z = pkhl(kv.z); qp.w = pkhl(kv.w);
      *(uint4*)&Qpk[row * 68 + 4 * c4] = qp;
      float ps = kv.x * kv.x + kv.y * kv.y + kv.z * kv.z + kv.w * kv.w;
      ps += __shfl_xor(ps, 1, 64); ps += __shfl_xor(ps, 2, 64);
      ps += __shfl_xor(ps, 4, 64); ps += __shfl_xor(ps, 8, 64);
      if (c4 == 0) ssq[row] = ps;
    }
  };

  load_tile(0);
  store_tile();
  __syncthreads();

  for (int tile = 0; tile < TPT; ++tile) {
    if (tile + 1 < TPT) load_tile(tile + 1);

    f32x4 X[4];
#pragma unroll
    for (int mt = 0; mt < 4; ++mt) X[mt] = (f32x4){0.f, 0.f, 0.f, 0.f};
#pragma unroll
    for (int ks = 0; ks < 2; ++ks) {
      const unsigned* qb = &Qpk[(16 * w + a) * 68 + 32 * ks + 8 * g];
      uint4 q0 = *(const uint4*)qb;
      uint4 q1 = *(const uint4*)(qb + 4);
      short8 ah = exhi(q0, q1), al = exlo(q0, q1);
#pragma unroll
      for (int mt = 0; mt < 4; ++mt) {
        X[mt] = __builtin_amdgcn_mfma_f32_16x16x32_bf16(ah, wfh[mt][ks], X[mt], 0, 0, 0);
        X[mt] = __builtin_amdgcn_mfma_f32_16x16x32_bf16(ah, wfl[mt][ks], X[mt], 0, 0, 0);
        X[mt] = __builtin_amdgcn_mfma_f32_16x16x32_bf16(al, wfh[mt][ks], X[mt], 0, 0, 0);
      }
    }

    float sq[4];
#pragma unroll
    for (int r = 0; r < 4; ++r) sq[r] = ssq[16 * w + 4 * g + r];
    float dv[4];
#pragma unroll
    for (int mt = 0; mt < 4; ++mt) dv[mt] = denv[16 * mt + a];
    float dn[4] = {0.f, 0.f, 0.f, 0.f};
#pragma unroll
    for (int mt = 0; mt < 4; ++mt) {
#pragma unroll
      for (int r = 0; r < 4; ++r) {
        float p_ = 0.125f * __expf(X[mt][r] - 0.5f * sq[r]);
        dn[r] = fmaf(p_, dv[mt], dn[r]);
        QP[(16 * w + 4 * g + r) * 68 + 16 * mt + a] = pkhl(p_);
      }
    }
#pragma unroll
    for (int r = 0; r < 4; ++r) {
      dn[r] += __shfl_xor(dn[r], 1, 64);
      dn[r] += __shfl_xor(dn[r], 2, 64);
      dn[r] += __shfl_xor(dn[r], 4, 64);
      dn[r] += __shfl_xor(dn[r], 8, 64);
    }
    __syncthreads();  // A

    f32x4 O[4];
#pragma unroll
    for (int ct = 0; ct < 4; ++ct) O[ct] = (f32x4){0.f, 0.f, 0.f, 0.f};
#pragma unroll
    for (int ks = 0; ks < 2; ++ks) {
      const unsigned* qb = &QP[(16 * w + a) * 68 + 32 * ks + 8 * g];
      uint4 r0 = *(const uint4*)qb;
      uint4 r1 = *(const uint4*)(qb + 4);
      short8 qh = exhi(r0, r1), ql = exlo(r0, r1);
#pragma unroll
      for (int ct = 0; ct < 4; ++ct) {
        short8 bh_ = *(const short8*)&B1h[(16 * ct + a) * 72 + 32 * ks + 8 * g];
        short8 bl_ = *(const short8*)&B1l[(16 * ct + a) * 72 + 32 * ks + 8 * g];
        O[ct] = __builtin_amdgcn_mfma_f32_16x16x32_bf16(qh, bh_, O[ct], 0, 0, 0);
        O[ct] = __builtin_amdgcn_mfma_f32_16x16x32_bf16(qh, bl_, O[ct], 0, 0, 0);
        O[ct] = __builtin_amdgcn_mfma_f32_16x16x32_bf16(ql, bh_, O[ct], 0, 0, 0);
      }
    }

    float inv[4];
#pragma unroll
    for (int r = 0; r < 4; ++r) inv[r] = 1.0f / dn[r];
    float* ob = out + ((size_t)bh * Sc + (size_t)ch * CH + tile * 64 + 16 * w + 4 * g) * 64;
#pragma unroll
    for (int ct = 0; ct < 4; ++ct)
#pragma unroll
      for (int r = 0; r < 4; ++r)
        ob[r * 64 + 16 * ct + a] = O[ct][r] * inv[r];
    __syncthreads();  // B
    if (tile + 1 < TPT) store_tile();
    __syncthreads();  // C
  }
}

extern "C" void kernel_launch(void* const* d_in, const int* in_sizes, int n_in,
                              void* d_out, int out_size, void* d_ws, size_t ws_size,
                              hipStream_t stream) {
  const float* Q = (const float*)d_in[0];
  const float* K = (const float*)d_in[1];
  const float* V = (const float*)d_in[2];
  const float* omega = (const float*)d_in[3];
  float* outp = (float*)d_out;
  float* b1 = (float*)d_ws;
  float* den = b1 + DEN_OFF;
  short* wT = (short*)((char*)d_ws + WT_OFF_BYTES);

  hipMemsetAsync(d_ws, 0, WT_OFF_BYTES, stream);  // zero b1 + den
  p0<<<16, 256, 0, stream>>>(omega, wT);
  p1<<<NH * NCHUNK, 256, 0, stream>>>(K, V, wT, b1, den);
  p2<<<NH * NCHUNK, 256, 0, stream>>>(Q, wT, b1, den, outp);
}